// Round 1
// baseline (810.497 us; speedup 1.0000x reference)
//
#include <hip/hip_runtime.h>
#include <hip/hip_bf16.h>

#define NN 100000
#define EE 3200000
#define GG 128
#define IN_DIM 16
#define HDIM 64
#define CDIM 4

// ---------------- CSR build ----------------

__global__ void count_deg_k(const int* __restrict__ dst, int* __restrict__ deg) {
    int e = blockIdx.x * 256 + threadIdx.x;
    if (e < EE) atomicAdd(&deg[dst[e]], 1);
}

__global__ void scan_pass1(const int* __restrict__ deg, int* __restrict__ bsum) {
    __shared__ int s[512];
    int i = blockIdx.x * 512 + threadIdx.x;
    int v = (i < NN) ? deg[i] : 0;
    s[threadIdx.x] = v;
    __syncthreads();
    for (int off = 256; off > 0; off >>= 1) {
        if (threadIdx.x < off) s[threadIdx.x] += s[threadIdx.x + off];
        __syncthreads();
    }
    if (threadIdx.x == 0) bsum[blockIdx.x] = s[0];
}

// exclusive scan of block sums (nblk <= 256), done in LDS to avoid a serial
// global-latency chain
__global__ void scan_pass2(int* __restrict__ bsum, int nblk, int* __restrict__ rowptr) {
    __shared__ int s[256];
    int t = threadIdx.x;
    s[t] = (t < nblk) ? bsum[t] : 0;
    __syncthreads();
    if (t == 0) {
        int run = 0;
        for (int i = 0; i < nblk; i++) { int v = s[i]; s[i] = run; run += v; }
        rowptr[NN] = run;   // == EE
    }
    __syncthreads();
    if (t < nblk) bsum[t] = s[t];
}

__global__ void scan_pass3(const int* __restrict__ deg, const int* __restrict__ bsum,
                           int* __restrict__ rowptr, int* __restrict__ cursor) {
    __shared__ int s[512];
    int t = threadIdx.x;
    int i = blockIdx.x * 512 + t;
    int v = (i < NN) ? deg[i] : 0;
    s[t] = v;
    __syncthreads();
    for (int off = 1; off < 512; off <<= 1) {
        int x = (t >= off) ? s[t - off] : 0;
        __syncthreads();
        s[t] += x;
        __syncthreads();
    }
    if (i < NN) {
        int excl = bsum[blockIdx.x] + s[t] - v;   // exclusive prefix
        rowptr[i] = excl;
        cursor[i] = excl;
    }
}

__global__ void fill_csr_k(const int* __restrict__ src, const int* __restrict__ dst,
                           int* __restrict__ cursor, int* __restrict__ srcS) {
    int e = blockIdx.x * 256 + threadIdx.x;
    if (e < EE) {
        int d = dst[e];
        int slot = atomicAdd(&cursor[d], 1);
        srcS[slot] = src[e];
    }
}

__global__ void dinv_k(const int* __restrict__ deg, float* __restrict__ dinv) {
    int i = blockIdx.x * 256 + threadIdx.x;
    if (i < NN) dinv[i] = rsqrtf((float)(deg[i] + 1));   // +1 self-loop
}

// ---------------- dense layers ----------------

// hs[n][j] = (x[n][:] @ W1[:,j]) * dinv[n]
__global__ void xw1_k(const float* __restrict__ x, const float* __restrict__ W1,
                      const float* __restrict__ dinv, float* __restrict__ hs) {
    __shared__ float Ws[IN_DIM * HDIM];
    int t = threadIdx.x;
    for (int i = t; i < IN_DIM * HDIM; i += 256) Ws[i] = W1[i];
    __syncthreads();
    int n = blockIdx.x * 4 + (t >> 6);
    int j = t & 63;
    if (n >= NN) return;
    const float* xr = x + (size_t)n * IN_DIM;
    float acc = 0.f;
#pragma unroll
    for (int k = 0; k < IN_DIM; k++) acc = fmaf(xr[k], Ws[k * HDIM + j], acc);
    hs[(size_t)n * HDIM + j] = acc * dinv[n];
}

// hs2[n][j] = (h1[n][:] @ W2[:,j]) * dinv[n]
__global__ void xw2_k(const float* __restrict__ h1, const float* __restrict__ W2,
                      const float* __restrict__ dinv, float* __restrict__ hs2) {
    __shared__ float Ws[HDIM * HDIM];      // 16 KB
    __shared__ float rows[4][HDIM];
    int t = threadIdx.x;
    for (int i = t; i < HDIM * HDIM; i += 256) Ws[i] = W2[i];
    int n = blockIdx.x * 4 + (t >> 6);
    int j = t & 63, w = t >> 6;
    float rv = (n < NN) ? h1[(size_t)n * HDIM + j] : 0.f;
    rows[w][j] = rv;
    __syncthreads();
    if (n >= NN) return;
    float acc = 0.f;
#pragma unroll
    for (int k = 0; k < HDIM; k++) acc = fmaf(rows[w][k], Ws[k * HDIM + j], acc);
    hs2[(size_t)n * HDIM + j] = acc * dinv[n];
}

// ---------------- aggregation (gather, 1 wave per node, lane = feature) ----------------

__global__ void agg_k(const float* __restrict__ hs, const int* __restrict__ rowptr,
                      const int* __restrict__ srcS, const float* __restrict__ dinv,
                      const float* __restrict__ bias, float* __restrict__ out) {
    int t = threadIdx.x;
    int n = blockIdx.x * 4 + (t >> 6);
    int lane = t & 63;
    if (n >= NN) return;
    int beg = rowptr[n], end = rowptr[n + 1];
    float acc = hs[(size_t)n * HDIM + lane];          // self-loop (already *dinv[n])
    int e = beg;
    for (; e + 4 <= end; e += 4) {
        int s0 = srcS[e], s1 = srcS[e + 1], s2 = srcS[e + 2], s3 = srcS[e + 3];
        float a0 = hs[(size_t)s0 * HDIM + lane];
        float a1 = hs[(size_t)s1 * HDIM + lane];
        float a2 = hs[(size_t)s2 * HDIM + lane];
        float a3 = hs[(size_t)s3 * HDIM + lane];
        acc += (a0 + a1) + (a2 + a3);
    }
    for (; e < end; ++e) acc += hs[(size_t)srcS[e] * HDIM + lane];
    float v = fmaf(acc, dinv[n], bias[lane]);
    out[(size_t)n * HDIM + lane] = fmaxf(v, 0.f);
}

// layer-2 aggregation fused with relu + global_add_pool
__global__ void agg_pool_k(const float* __restrict__ hs, const int* __restrict__ rowptr,
                           const int* __restrict__ srcS, const float* __restrict__ dinv,
                           const float* __restrict__ bias, const int* __restrict__ batch,
                           float* __restrict__ g) {
    int t = threadIdx.x;
    int n = blockIdx.x * 4 + (t >> 6);
    int lane = t & 63;
    if (n >= NN) return;
    int beg = rowptr[n], end = rowptr[n + 1];
    float acc = hs[(size_t)n * HDIM + lane];
    int e = beg;
    for (; e + 4 <= end; e += 4) {
        int s0 = srcS[e], s1 = srcS[e + 1], s2 = srcS[e + 2], s3 = srcS[e + 3];
        float a0 = hs[(size_t)s0 * HDIM + lane];
        float a1 = hs[(size_t)s1 * HDIM + lane];
        float a2 = hs[(size_t)s2 * HDIM + lane];
        float a3 = hs[(size_t)s3 * HDIM + lane];
        acc += (a0 + a1) + (a2 + a3);
    }
    for (; e < end; ++e) acc += hs[(size_t)srcS[e] * HDIM + lane];
    float v = fmaf(acc, dinv[n], bias[lane]);
    v = fmaxf(v, 0.f);
    unsafeAtomicAdd(&g[(size_t)batch[n] * HDIM + lane], v);
}

// out[g][c] = g[g][:] @ Wl[:,c] + bl[c]
__global__ void final_k(const float* __restrict__ g, const float* __restrict__ Wl,
                        const float* __restrict__ bl, float* __restrict__ out) {
    int t = threadIdx.x;          // 512 = 128 graphs * 4 classes
    int gi = t >> 2, c = t & 3;
    float acc = bl[c];
#pragma unroll
    for (int k = 0; k < HDIM; k++) acc = fmaf(g[gi * HDIM + k], Wl[k * CDIM + c], acc);
    out[gi * CDIM + c] = acc;
}

// ---------------- launch ----------------

extern "C" void kernel_launch(void* const* d_in, const int* in_sizes, int n_in,
                              void* d_out, int out_size, void* d_ws, size_t ws_size,
                              hipStream_t stream) {
    const float* x   = (const float*)d_in[0];
    const int*   ei  = (const int*)d_in[1];
    const int*   src = ei;
    const int*   dst = ei + EE;
    const int*   batch = (const int*)d_in[2];
    const float* W1 = (const float*)d_in[3];
    const float* b1 = (const float*)d_in[4];
    const float* W2 = (const float*)d_in[5];
    const float* b2 = (const float*)d_in[6];
    const float* Wl = (const float*)d_in[7];
    const float* bl = (const float*)d_in[8];
    float* out = (float*)d_out;

    char* w = (char*)d_ws;
    auto alloc = [&](size_t bytes) -> char* {
        char* p = w;
        w += (bytes + 255) & ~(size_t)255;
        return p;
    };
    int*   deg    = (int*)alloc((size_t)NN * 4);
    int*   rowptr = (int*)alloc((size_t)(NN + 1) * 4);
    int*   cursor = (int*)alloc((size_t)NN * 4);
    int*   bsum   = (int*)alloc(256 * 4);
    int*   srcS   = (int*)alloc((size_t)EE * 4);
    float* dinv   = (float*)alloc((size_t)NN * 4);
    float* hA     = (float*)alloc((size_t)NN * HDIM * 4);
    float* hB     = (float*)alloc((size_t)NN * HDIM * 4);
    float* g      = (float*)alloc((size_t)GG * HDIM * 4);

    const int NBLK = (NN + 511) / 512;   // 196

    hipMemsetAsync(deg, 0, (size_t)NN * 4, stream);
    hipMemsetAsync(g, 0, (size_t)GG * HDIM * 4, stream);

    count_deg_k<<<(EE + 255) / 256, 256, 0, stream>>>(dst, deg);
    scan_pass1<<<NBLK, 512, 0, stream>>>(deg, bsum);
    scan_pass2<<<1, 256, 0, stream>>>(bsum, NBLK, rowptr);
    scan_pass3<<<NBLK, 512, 0, stream>>>(deg, bsum, rowptr, cursor);
    fill_csr_k<<<(EE + 255) / 256, 256, 0, stream>>>(src, dst, cursor, srcS);
    dinv_k<<<(NN + 255) / 256, 256, 0, stream>>>(deg, dinv);

    xw1_k<<<(NN + 3) / 4, 256, 0, stream>>>(x, W1, dinv, hA);
    agg_k<<<(NN + 3) / 4, 256, 0, stream>>>(hA, rowptr, srcS, dinv, b1, hB);
    xw2_k<<<(NN + 3) / 4, 256, 0, stream>>>(hB, W2, dinv, hA);
    agg_pool_k<<<(NN + 3) / 4, 256, 0, stream>>>(hA, rowptr, srcS, dinv, b2, batch, g);
    final_k<<<1, 512, 0, stream>>>(g, Wl, bl, out);
}

// Round 2
// 561.474 us; speedup vs baseline: 1.4435x; 1.4435x over previous
//
#include <hip/hip_runtime.h>
#include <hip/hip_bf16.h>

#define NN 100000
#define EE 3200000
#define GG 128
#define IN_DIM 16
#define HDIM 64
#define CDIM 4

#define RN 256                    // nodes per bucket
#define NB ((NN + RN - 1) / RN)   // 391 buckets
#define CH 8192                   // edges per partition block

// ---------------- degree ----------------

__global__ void count_deg_k(const int* __restrict__ dst, int* __restrict__ deg) {
    int e = blockIdx.x * 256 + threadIdx.x;
    if (e < EE) atomicAdd(&deg[dst[e]], 1);
}

// per-bucket edge count (sum of deg over the bucket's node range), fused dinv
__global__ void bucketcnt_k(const int* __restrict__ deg, float* __restrict__ dinv,
                            int* __restrict__ bcnt) {
    __shared__ int s[256];
    int b = blockIdx.x, t = threadIdx.x;
    int n = (b << 8) + t;
    int d = (n < NN) ? deg[n] : 0;
    if (n < NN) dinv[n] = rsqrtf((float)(d + 1));   // +1 self-loop
    s[t] = d;
    __syncthreads();
    for (int off = 128; off > 0; off >>= 1) {
        if (t < off) s[t] += s[t + off];
        __syncthreads();
    }
    if (t == 0) bcnt[b] = s[0];
}

// exclusive scan of bucket counts -> bucketBase, init gcursor
__global__ void bucketscan_k(const int* __restrict__ bcnt, int* __restrict__ bucketBase,
                             int* __restrict__ gcursor) {
    __shared__ int s[512];
    int t = threadIdx.x;
    s[t] = (t < NB) ? bcnt[t] : 0;
    __syncthreads();
    for (int off = 1; off < 512; off <<= 1) {
        int v = (t >= off) ? s[t - off] : 0;
        __syncthreads();
        s[t] += v;
        __syncthreads();
    }
    if (t < NB) {
        int base = s[t] - bcnt[t];
        bucketBase[t] = base;
        gcursor[t] = base;
    }
    if (t == 0) bucketBase[NB] = EE;
}

// ---------------- partition: edges -> bucket-grouped packed pairs ----------------
// packed pair: (src << 8) | (dst & 255); src < 2^17 so fits u32

__global__ __launch_bounds__(512) void partition_k(const int* __restrict__ src,
                                                   const int* __restrict__ dst,
                                                   int* __restrict__ gcursor,
                                                   unsigned int* __restrict__ pairs) {
    __shared__ int hist[NB];
    __shared__ int lbase[NB];
    __shared__ int gbase[NB];
    __shared__ int scanbuf[512];
    __shared__ unsigned int stag[CH];
    __shared__ unsigned short stagb[CH];
    int t = threadIdx.x;
    long e0 = (long)blockIdx.x * CH;
    int cnt = (int)min((long)CH, (long)EE - e0);

    for (int i = t; i < NB; i += 512) hist[i] = 0;
    __syncthreads();

    int myb[16], myloc[16];
    unsigned int myp[16];
#pragma unroll
    for (int r = 0; r < 16; ++r) {
        int i = t + (r << 9);
        if (i < cnt) {
            int s = src[e0 + i], d = dst[e0 + i];
            int b = d >> 8;
            myb[r] = b;
            myp[r] = ((unsigned int)s << 8) | (unsigned int)(d & 255);
            myloc[r] = atomicAdd(&hist[b], 1);
        } else {
            myb[r] = -1;
            myloc[r] = 0;
            myp[r] = 0;
        }
    }
    __syncthreads();

    // exclusive scan of hist -> lbase
    scanbuf[t] = (t < NB) ? hist[t] : 0;
    __syncthreads();
    for (int off = 1; off < 512; off <<= 1) {
        int v = (t >= off) ? scanbuf[t - off] : 0;
        __syncthreads();
        scanbuf[t] += v;
        __syncthreads();
    }
    if (t < NB) {
        lbase[t] = scanbuf[t] - hist[t];
        gbase[t] = (hist[t] > 0) ? atomicAdd(&gcursor[t], hist[t]) : 0;
    }
    __syncthreads();

    // scatter into LDS staging, grouped by bucket
#pragma unroll
    for (int r = 0; r < 16; ++r) {
        if (myb[r] >= 0) {
            int pos = lbase[myb[r]] + myloc[r];
            stag[pos] = myp[r];
            stagb[pos] = (unsigned short)myb[r];
        }
    }
    __syncthreads();

    // flush runs to global; consecutive i within a run -> consecutive global addr
    for (int i = t; i < cnt; i += 512) {
        int b = stagb[i];
        pairs[gbase[b] + (i - lbase[b])] = stag[i];
    }
}

// ---------------- per-bucket CSR fill (L2-local scatter) ----------------

__global__ __launch_bounds__(512) void csrfill_k(const int* __restrict__ deg,
                                                 const int* __restrict__ bucketBase,
                                                 const unsigned int* __restrict__ pairs,
                                                 int* __restrict__ rowptr,
                                                 int* __restrict__ srcS) {
    __shared__ int sb[256];
    __shared__ int lcur[256];
    int b = blockIdx.x, t = threadIdx.x;
    int n0 = b << 8;
    int gb = bucketBase[b];
    int gend = bucketBase[b + 1];

    int d = 0;
    if (t < 256) {
        int n = n0 + t;
        d = (n < NN) ? deg[n] : 0;
        sb[t] = d;
    }
    __syncthreads();
    for (int off = 1; off < 256; off <<= 1) {
        int v = 0;
        if (t < 256 && t >= off) v = sb[t - off];
        __syncthreads();
        if (t < 256) sb[t] += v;
        __syncthreads();
    }
    if (t < 256) {
        int excl = sb[t] - d;
        int n = n0 + t;
        if (n < NN) rowptr[n] = gb + excl;
        lcur[t] = excl;
    }
    if (b == 0 && t == 0) rowptr[NN] = EE;
    __syncthreads();

    for (int idx = gb + t; idx < gend; idx += 512) {
        unsigned int p = pairs[idx];
        int dl = (int)(p & 255u);
        int s = (int)(p >> 8);
        int slot = atomicAdd(&lcur[dl], 1);
        srcS[gb + slot] = s;
    }
}

// ---------------- dense layers ----------------

__global__ void xw1_k(const float* __restrict__ x, const float* __restrict__ W1,
                      const float* __restrict__ dinv, float* __restrict__ hs) {
    __shared__ float Ws[IN_DIM * HDIM];
    int t = threadIdx.x;
    for (int i = t; i < IN_DIM * HDIM; i += 256) Ws[i] = W1[i];
    __syncthreads();
    int n = blockIdx.x * 4 + (t >> 6);
    int j = t & 63;
    if (n >= NN) return;
    const float* xr = x + (size_t)n * IN_DIM;
    float acc = 0.f;
#pragma unroll
    for (int k = 0; k < IN_DIM; k++) acc = fmaf(xr[k], Ws[k * HDIM + j], acc);
    hs[(size_t)n * HDIM + j] = acc * dinv[n];
}

__global__ void xw2_k(const float* __restrict__ h1, const float* __restrict__ W2,
                      const float* __restrict__ dinv, float* __restrict__ hs2) {
    __shared__ float Ws[HDIM * HDIM];
    __shared__ float rows[4][HDIM];
    int t = threadIdx.x;
    for (int i = t; i < HDIM * HDIM; i += 256) Ws[i] = W2[i];
    int n = blockIdx.x * 4 + (t >> 6);
    int j = t & 63, w = t >> 6;
    float rv = (n < NN) ? h1[(size_t)n * HDIM + j] : 0.f;
    rows[w][j] = rv;
    __syncthreads();
    if (n >= NN) return;
    float acc = 0.f;
#pragma unroll
    for (int k = 0; k < HDIM; k++) acc = fmaf(rows[w][k], Ws[k * HDIM + j], acc);
    hs2[(size_t)n * HDIM + j] = acc * dinv[n];
}

// ---------------- aggregation (gather, 1 wave per node, lane = feature) ----------------

__global__ void agg_k(const float* __restrict__ hs, const int* __restrict__ rowptr,
                      const int* __restrict__ srcS, const float* __restrict__ dinv,
                      const float* __restrict__ bias, float* __restrict__ out) {
    int t = threadIdx.x;
    int n = blockIdx.x * 4 + (t >> 6);
    int lane = t & 63;
    if (n >= NN) return;
    int beg = rowptr[n], end = rowptr[n + 1];
    float acc = hs[(size_t)n * HDIM + lane];          // self-loop
    int e = beg;
    for (; e + 8 <= end; e += 8) {
        int s0 = srcS[e],     s1 = srcS[e + 1], s2 = srcS[e + 2], s3 = srcS[e + 3];
        int s4 = srcS[e + 4], s5 = srcS[e + 5], s6 = srcS[e + 6], s7 = srcS[e + 7];
        float a0 = hs[(size_t)s0 * HDIM + lane];
        float a1 = hs[(size_t)s1 * HDIM + lane];
        float a2 = hs[(size_t)s2 * HDIM + lane];
        float a3 = hs[(size_t)s3 * HDIM + lane];
        float a4 = hs[(size_t)s4 * HDIM + lane];
        float a5 = hs[(size_t)s5 * HDIM + lane];
        float a6 = hs[(size_t)s6 * HDIM + lane];
        float a7 = hs[(size_t)s7 * HDIM + lane];
        acc += ((a0 + a1) + (a2 + a3)) + ((a4 + a5) + (a6 + a7));
    }
    for (; e < end; ++e) acc += hs[(size_t)srcS[e] * HDIM + lane];
    float v = fmaf(acc, dinv[n], bias[lane]);
    out[(size_t)n * HDIM + lane] = fmaxf(v, 0.f);
}

__global__ void agg_pool_k(const float* __restrict__ hs, const int* __restrict__ rowptr,
                           const int* __restrict__ srcS, const float* __restrict__ dinv,
                           const float* __restrict__ bias, const int* __restrict__ batch,
                           float* __restrict__ g) {
    int t = threadIdx.x;
    int n = blockIdx.x * 4 + (t >> 6);
    int lane = t & 63;
    if (n >= NN) return;
    int beg = rowptr[n], end = rowptr[n + 1];
    float acc = hs[(size_t)n * HDIM + lane];
    int e = beg;
    for (; e + 8 <= end; e += 8) {
        int s0 = srcS[e],     s1 = srcS[e + 1], s2 = srcS[e + 2], s3 = srcS[e + 3];
        int s4 = srcS[e + 4], s5 = srcS[e + 5], s6 = srcS[e + 6], s7 = srcS[e + 7];
        float a0 = hs[(size_t)s0 * HDIM + lane];
        float a1 = hs[(size_t)s1 * HDIM + lane];
        float a2 = hs[(size_t)s2 * HDIM + lane];
        float a3 = hs[(size_t)s3 * HDIM + lane];
        float a4 = hs[(size_t)s4 * HDIM + lane];
        float a5 = hs[(size_t)s5 * HDIM + lane];
        float a6 = hs[(size_t)s6 * HDIM + lane];
        float a7 = hs[(size_t)s7 * HDIM + lane];
        acc += ((a0 + a1) + (a2 + a3)) + ((a4 + a5) + (a6 + a7));
    }
    for (; e < end; ++e) acc += hs[(size_t)srcS[e] * HDIM + lane];
    float v = fmaf(acc, dinv[n], bias[lane]);
    v = fmaxf(v, 0.f);
    unsafeAtomicAdd(&g[(size_t)batch[n] * HDIM + lane], v);
}

__global__ void final_k(const float* __restrict__ g, const float* __restrict__ Wl,
                        const float* __restrict__ bl, float* __restrict__ out) {
    int t = threadIdx.x;
    int gi = t >> 2, c = t & 3;
    float acc = bl[c];
#pragma unroll
    for (int k = 0; k < HDIM; k++) acc = fmaf(g[gi * HDIM + k], Wl[k * CDIM + c], acc);
    out[gi * CDIM + c] = acc;
}

// ---------------- launch ----------------

extern "C" void kernel_launch(void* const* d_in, const int* in_sizes, int n_in,
                              void* d_out, int out_size, void* d_ws, size_t ws_size,
                              hipStream_t stream) {
    const float* x   = (const float*)d_in[0];
    const int*   ei  = (const int*)d_in[1];
    const int*   src = ei;
    const int*   dst = ei + EE;
    const int*   batch = (const int*)d_in[2];
    const float* W1 = (const float*)d_in[3];
    const float* b1 = (const float*)d_in[4];
    const float* W2 = (const float*)d_in[5];
    const float* b2 = (const float*)d_in[6];
    const float* Wl = (const float*)d_in[7];
    const float* bl = (const float*)d_in[8];
    float* out = (float*)d_out;

    char* w = (char*)d_ws;
    auto alloc = [&](size_t bytes) -> char* {
        char* p = w;
        w += (bytes + 255) & ~(size_t)255;
        return p;
    };
    int*   deg        = (int*)alloc((size_t)NN * 4);
    int*   rowptr     = (int*)alloc((size_t)(NN + 1) * 4);
    int*   bcnt       = (int*)alloc((size_t)NB * 4);
    int*   bucketBase = (int*)alloc((size_t)(NB + 1) * 4);
    int*   gcursor    = (int*)alloc((size_t)NB * 4);
    unsigned int* pairs = (unsigned int*)alloc((size_t)EE * 4);
    int*   srcS       = (int*)alloc((size_t)EE * 4);
    float* dinv       = (float*)alloc((size_t)NN * 4);
    float* hA         = (float*)alloc((size_t)NN * HDIM * 4);
    float* hB         = (float*)alloc((size_t)NN * HDIM * 4);
    float* g          = (float*)alloc((size_t)GG * HDIM * 4);

    hipMemsetAsync(deg, 0, (size_t)NN * 4, stream);
    hipMemsetAsync(g, 0, (size_t)GG * HDIM * 4, stream);

    count_deg_k<<<(EE + 255) / 256, 256, 0, stream>>>(dst, deg);
    bucketcnt_k<<<NB, 256, 0, stream>>>(deg, dinv, bcnt);
    bucketscan_k<<<1, 512, 0, stream>>>(bcnt, bucketBase, gcursor);
    partition_k<<<(EE + CH - 1) / CH, 512, 0, stream>>>(src, dst, gcursor, pairs);
    csrfill_k<<<NB, 512, 0, stream>>>(deg, bucketBase, pairs, rowptr, srcS);

    xw1_k<<<(NN + 3) / 4, 256, 0, stream>>>(x, W1, dinv, hA);
    agg_k<<<(NN + 3) / 4, 256, 0, stream>>>(hA, rowptr, srcS, dinv, b1, hB);
    xw2_k<<<(NN + 3) / 4, 256, 0, stream>>>(hB, W2, dinv, hA);
    agg_pool_k<<<(NN + 3) / 4, 256, 0, stream>>>(hA, rowptr, srcS, dinv, b2, batch, g);
    final_k<<<1, 512, 0, stream>>>(g, Wl, bl, out);
}

// Round 3
// 387.871 us; speedup vs baseline: 2.0896x; 1.4476x over previous
//
#include <hip/hip_runtime.h>
#include <hip/hip_bf16.h>

#define NN 100000
#define EE 3200000
#define GG 128
#define IN_DIM 16
#define HDIM 64
#define CDIM 4

#define RN 256                    // nodes per bucket
#define NB ((NN + RN - 1) / RN)   // 391 buckets
#define CH 8192                   // edges per partition block

typedef unsigned short u16;
typedef unsigned int u32;

__device__ __forceinline__ float bf2f(u16 u) {
    u32 x = ((u32)u) << 16;
    float f;
    __builtin_memcpy(&f, &x, 4);
    return f;
}
__device__ __forceinline__ u16 f2bf(float f) {
    u32 x;
    __builtin_memcpy(&x, &f, 4);
    u32 r = (x + 0x7FFFu + ((x >> 16) & 1u)) >> 16;   // RNE
    return (u16)r;
}

// ---------------- bucket histogram (replaces per-node count_deg) ----------------

__global__ __launch_bounds__(512) void bhist_k(const int* __restrict__ dst,
                                               int* __restrict__ bcnt) {
    __shared__ int hist[NB];
    int t = threadIdx.x;
    long e0 = (long)blockIdx.x * CH;
    int cnt = (int)min((long)CH, (long)EE - e0);
    for (int i = t; i < NB; i += 512) hist[i] = 0;
    __syncthreads();
    for (int i = t; i < cnt; i += 512) atomicAdd(&hist[dst[e0 + i] >> 8], 1);
    __syncthreads();
    for (int i = t; i < NB; i += 512) {
        int v = hist[i];
        if (v > 0) atomicAdd(&bcnt[i], v);
    }
}

// exclusive scan of bucket counts -> bucketBase, init gcursor
__global__ void bucketscan_k(const int* __restrict__ bcnt, int* __restrict__ bucketBase,
                             int* __restrict__ gcursor) {
    __shared__ int s[512];
    int t = threadIdx.x;
    int c = (t < NB) ? bcnt[t] : 0;
    s[t] = c;
    __syncthreads();
    for (int off = 1; off < 512; off <<= 1) {
        int v = (t >= off) ? s[t - off] : 0;
        __syncthreads();
        s[t] += v;
        __syncthreads();
    }
    if (t < NB) {
        int base = s[t] - c;
        bucketBase[t] = base;
        gcursor[t] = base;
    }
    if (t == 0) bucketBase[NB] = EE;
}

// ---------------- partition: edges -> bucket-grouped packed pairs ----------------
// packed pair: (src << 8) | (dst & 255)

__global__ __launch_bounds__(512) void partition_k(const int* __restrict__ src,
                                                   const int* __restrict__ dst,
                                                   int* __restrict__ gcursor,
                                                   u32* __restrict__ pairs) {
    __shared__ int hist[NB];
    __shared__ int lbase[NB];
    __shared__ int gbase[NB];
    __shared__ int scanbuf[512];
    __shared__ u32 stag[CH];
    __shared__ u16 stagb[CH];
    int t = threadIdx.x;
    long e0 = (long)blockIdx.x * CH;
    int cnt = (int)min((long)CH, (long)EE - e0);

    for (int i = t; i < NB; i += 512) hist[i] = 0;
    __syncthreads();

    int myb[16], myloc[16];
    u32 myp[16];
#pragma unroll
    for (int r = 0; r < 16; ++r) {
        int i = t + (r << 9);
        if (i < cnt) {
            int s = src[e0 + i], d = dst[e0 + i];
            int b = d >> 8;
            myb[r] = b;
            myp[r] = ((u32)s << 8) | (u32)(d & 255);
            myloc[r] = atomicAdd(&hist[b], 1);
        } else {
            myb[r] = -1;
            myloc[r] = 0;
            myp[r] = 0;
        }
    }
    __syncthreads();

    scanbuf[t] = (t < NB) ? hist[t] : 0;
    __syncthreads();
    for (int off = 1; off < 512; off <<= 1) {
        int v = (t >= off) ? scanbuf[t - off] : 0;
        __syncthreads();
        scanbuf[t] += v;
        __syncthreads();
    }
    if (t < NB) {
        lbase[t] = scanbuf[t] - hist[t];
        gbase[t] = (hist[t] > 0) ? atomicAdd(&gcursor[t], hist[t]) : 0;
    }
    __syncthreads();

#pragma unroll
    for (int r = 0; r < 16; ++r) {
        if (myb[r] >= 0) {
            int pos = lbase[myb[r]] + myloc[r];
            stag[pos] = myp[r];
            stagb[pos] = (u16)myb[r];
        }
    }
    __syncthreads();

    for (int i = t; i < cnt; i += 512) {
        int b = stagb[i];
        pairs[gbase[b] + (i - lbase[b])] = stag[i];
    }
}

// ---------------- per-bucket CSR fill: local deg count + dinv + rowptr + scatter --------

__global__ __launch_bounds__(512) void csrfill_k(const int* __restrict__ bucketBase,
                                                 const u32* __restrict__ pairs,
                                                 int* __restrict__ rowptr,
                                                 float* __restrict__ dinv,
                                                 int* __restrict__ srcS) {
    __shared__ int sb[256];     // deg, then inclusive scan
    __shared__ int sdeg[256];
    __shared__ int lcur[256];
    int b = blockIdx.x, t = threadIdx.x;
    int n0 = b << 8;
    int gb = bucketBase[b];
    int gend = bucketBase[b + 1];

    if (t < 256) sb[t] = 0;
    __syncthreads();

    // pass A: per-node degree via LDS atomics
    for (int idx = gb + t; idx < gend; idx += 512) atomicAdd(&sb[pairs[idx] & 255u], 1);
    __syncthreads();

    int d = (t < 256) ? sb[t] : 0;
    if (t < 256) {
        sdeg[t] = d;
        int n = n0 + t;
        if (n < NN) dinv[n] = rsqrtf((float)(d + 1));   // +1 self-loop
    }
    __syncthreads();
    // inclusive scan over 256 entries (done by threads 0..255)
    for (int off = 1; off < 256; off <<= 1) {
        int v = 0;
        if (t < 256 && t >= off) v = sb[t - off];
        __syncthreads();
        if (t < 256) sb[t] += v;
        __syncthreads();
    }
    if (t < 256) {
        int excl = sb[t] - sdeg[t];
        int n = n0 + t;
        if (n < NN) rowptr[n] = gb + excl;
        lcur[t] = excl;
    }
    if (b == 0 && t == 0) rowptr[NN] = EE;
    __syncthreads();

    // pass B: place
    for (int idx = gb + t; idx < gend; idx += 512) {
        u32 p = pairs[idx];
        int dl = (int)(p & 255u);
        int slot = atomicAdd(&lcur[dl], 1);
        srcS[gb + slot] = (int)(p >> 8);
    }
}

// ---------------- layer 1 dense: hs[n][j] = (x[n]@W1)[j] * dinv[n]  (bf16 out) --------

__global__ void xw1_k(const float* __restrict__ x, const float* __restrict__ W1,
                      const float* __restrict__ dinv, u16* __restrict__ hs) {
    __shared__ float Ws[IN_DIM * HDIM];
    __shared__ float xs[4 * IN_DIM];
    int t = threadIdx.x;
    for (int i = t; i < IN_DIM * HDIM; i += 256) Ws[i] = W1[i];
    if (t < 4 * IN_DIM) {
        int n = blockIdx.x * 4 + (t >> 4);
        xs[t] = (n < NN) ? x[(size_t)blockIdx.x * 4 * IN_DIM + t] : 0.f;
    }
    __syncthreads();
    int n = blockIdx.x * 4 + (t >> 6);
    int j = t & 63, w = t >> 6;
    if (n >= NN) return;
    float acc = 0.f;
#pragma unroll
    for (int k = 0; k < IN_DIM; k++) acc = fmaf(xs[w * IN_DIM + k], Ws[k * HDIM + j], acc);
    hs[(size_t)n * HDIM + j] = f2bf(acc * dinv[n]);
}

// ---------------- agg layer 1 fused with @W2 and pre-scale (bf16 in/out) ----------------
// out2[n][j] = dinv[n] * sum_k relu(agg1[n][k] + b1[k]) * W2[k][j]

__global__ __launch_bounds__(256) void agg1w2_k(const u16* __restrict__ hs,
                                                const int* __restrict__ rowptr,
                                                const int* __restrict__ srcS,
                                                const float* __restrict__ dinv,
                                                const float* __restrict__ b1,
                                                const float* __restrict__ W2,
                                                u16* __restrict__ hs2) {
    __shared__ float Ws[HDIM * HDIM];   // 16 KB
    __shared__ float rows[4][HDIM];
    int t = threadIdx.x;
    for (int i = t; i < HDIM * HDIM; i += 256) Ws[i] = W2[i];

    int n = blockIdx.x * 4 + (t >> 6);
    int lane = t & 63, w = t >> 6;
    int beg = rowptr[n], end = rowptr[n + 1];
    float acc = bf2f(hs[(size_t)n * HDIM + lane]);   // self-loop (pre-scaled)
    int e = beg;
    for (; e + 8 <= end; e += 8) {
        int s0 = srcS[e],     s1 = srcS[e + 1], s2 = srcS[e + 2], s3 = srcS[e + 3];
        int s4 = srcS[e + 4], s5 = srcS[e + 5], s6 = srcS[e + 6], s7 = srcS[e + 7];
        float a0 = bf2f(hs[(size_t)s0 * HDIM + lane]);
        float a1 = bf2f(hs[(size_t)s1 * HDIM + lane]);
        float a2 = bf2f(hs[(size_t)s2 * HDIM + lane]);
        float a3 = bf2f(hs[(size_t)s3 * HDIM + lane]);
        float a4 = bf2f(hs[(size_t)s4 * HDIM + lane]);
        float a5 = bf2f(hs[(size_t)s5 * HDIM + lane]);
        float a6 = bf2f(hs[(size_t)s6 * HDIM + lane]);
        float a7 = bf2f(hs[(size_t)s7 * HDIM + lane]);
        acc += ((a0 + a1) + (a2 + a3)) + ((a4 + a5) + (a6 + a7));
    }
    for (; e < end; ++e) acc += bf2f(hs[(size_t)srcS[e] * HDIM + lane]);
    float v = fmaf(acc, dinv[n], b1[lane]);
    rows[w][lane] = fmaxf(v, 0.f);                   // h1 row
    __syncthreads();

    float acc2 = 0.f;
#pragma unroll
    for (int k = 0; k < HDIM; k++) acc2 = fmaf(rows[w][k], Ws[k * HDIM + lane], acc2);
    hs2[(size_t)n * HDIM + lane] = f2bf(acc2 * dinv[n]);
}

// ---------------- agg layer 2 fused with relu + global_add_pool ----------------

__global__ __launch_bounds__(256) void agg_pool_k(const u16* __restrict__ hs,
                                                  const int* __restrict__ rowptr,
                                                  const int* __restrict__ srcS,
                                                  const float* __restrict__ dinv,
                                                  const float* __restrict__ b2,
                                                  const int* __restrict__ batch,
                                                  float* __restrict__ g) {
    int t = threadIdx.x;
    int n = blockIdx.x * 4 + (t >> 6);
    int lane = t & 63;
    int beg = rowptr[n], end = rowptr[n + 1];
    float acc = bf2f(hs[(size_t)n * HDIM + lane]);
    int e = beg;
    for (; e + 8 <= end; e += 8) {
        int s0 = srcS[e],     s1 = srcS[e + 1], s2 = srcS[e + 2], s3 = srcS[e + 3];
        int s4 = srcS[e + 4], s5 = srcS[e + 5], s6 = srcS[e + 6], s7 = srcS[e + 7];
        float a0 = bf2f(hs[(size_t)s0 * HDIM + lane]);
        float a1 = bf2f(hs[(size_t)s1 * HDIM + lane]);
        float a2 = bf2f(hs[(size_t)s2 * HDIM + lane]);
        float a3 = bf2f(hs[(size_t)s3 * HDIM + lane]);
        float a4 = bf2f(hs[(size_t)s4 * HDIM + lane]);
        float a5 = bf2f(hs[(size_t)s5 * HDIM + lane]);
        float a6 = bf2f(hs[(size_t)s6 * HDIM + lane]);
        float a7 = bf2f(hs[(size_t)s7 * HDIM + lane]);
        acc += ((a0 + a1) + (a2 + a3)) + ((a4 + a5) + (a6 + a7));
    }
    for (; e < end; ++e) acc += bf2f(hs[(size_t)srcS[e] * HDIM + lane]);
    float v = fmaf(acc, dinv[n], b2[lane]);
    v = fmaxf(v, 0.f);
    unsafeAtomicAdd(&g[(size_t)batch[n] * HDIM + lane], v);
}

__global__ void final_k(const float* __restrict__ g, const float* __restrict__ Wl,
                        const float* __restrict__ bl, float* __restrict__ out) {
    int t = threadIdx.x;
    int gi = t >> 2, c = t & 3;
    float acc = bl[c];
#pragma unroll
    for (int k = 0; k < HDIM; k++) acc = fmaf(g[gi * HDIM + k], Wl[k * CDIM + c], acc);
    out[gi * CDIM + c] = acc;
}

// ---------------- launch ----------------

extern "C" void kernel_launch(void* const* d_in, const int* in_sizes, int n_in,
                              void* d_out, int out_size, void* d_ws, size_t ws_size,
                              hipStream_t stream) {
    const float* x   = (const float*)d_in[0];
    const int*   ei  = (const int*)d_in[1];
    const int*   src = ei;
    const int*   dst = ei + EE;
    const int*   batch = (const int*)d_in[2];
    const float* W1 = (const float*)d_in[3];
    const float* b1 = (const float*)d_in[4];
    const float* W2 = (const float*)d_in[5];
    const float* b2 = (const float*)d_in[6];
    const float* Wl = (const float*)d_in[7];
    const float* bl = (const float*)d_in[8];
    float* out = (float*)d_out;

    char* w = (char*)d_ws;
    auto alloc = [&](size_t bytes) -> char* {
        char* p = w;
        w += (bytes + 255) & ~(size_t)255;
        return p;
    };
    int*   bcnt       = (int*)alloc((size_t)NB * 4);
    int*   bucketBase = (int*)alloc((size_t)(NB + 1) * 4);
    int*   gcursor    = (int*)alloc((size_t)NB * 4);
    u32*   pairs      = (u32*)alloc((size_t)EE * 4);
    int*   srcS       = (int*)alloc((size_t)EE * 4);
    int*   rowptr     = (int*)alloc((size_t)(NN + 1) * 4);
    float* dinv       = (float*)alloc((size_t)NN * 4);
    u16*   hsA        = (u16*)alloc((size_t)NN * HDIM * 2);
    u16*   hsB        = (u16*)alloc((size_t)NN * HDIM * 2);
    float* g          = (float*)alloc((size_t)GG * HDIM * 4);

    hipMemsetAsync(bcnt, 0, (size_t)NB * 4, stream);
    hipMemsetAsync(g, 0, (size_t)GG * HDIM * 4, stream);

    const int NCHUNK = (EE + CH - 1) / CH;   // 391
    bhist_k<<<NCHUNK, 512, 0, stream>>>(dst, bcnt);
    bucketscan_k<<<1, 512, 0, stream>>>(bcnt, bucketBase, gcursor);
    partition_k<<<NCHUNK, 512, 0, stream>>>(src, dst, gcursor, pairs);
    csrfill_k<<<NB, 512, 0, stream>>>(bucketBase, pairs, rowptr, dinv, srcS);

    xw1_k<<<(NN + 3) / 4, 256, 0, stream>>>(x, W1, dinv, hsA);
    agg1w2_k<<<(NN + 3) / 4, 256, 0, stream>>>(hsA, rowptr, srcS, dinv, b1, W2, hsB);
    agg_pool_k<<<(NN + 3) / 4, 256, 0, stream>>>(hsB, rowptr, srcS, dinv, b2, batch, g);
    final_k<<<1, 512, 0, stream>>>(g, Wl, bl, out);
}

// Round 4
// 328.540 us; speedup vs baseline: 2.4670x; 1.1806x over previous
//
#include <hip/hip_runtime.h>
#include <hip/hip_bf16.h>

#define NN 100000
#define EE 3200000
#define GG 128
#define IN_DIM 16
#define HDIM 64
#define CDIM 4

#define RN 256                    // nodes per bucket
#define NB ((NN + RN - 1) / RN)   // 391 buckets
#define CH 8192                   // edges per partition block

typedef unsigned short u16;
typedef unsigned int u32;

__device__ __forceinline__ float bf_lo(u32 w) { return __uint_as_float(w << 16); }
__device__ __forceinline__ float bf_hi(u32 w) { return __uint_as_float(w & 0xFFFF0000u); }
__device__ __forceinline__ u16 f2bf(float f) {
    u32 x = __float_as_uint(f);
    return (u16)((x + 0x7FFFu + ((x >> 16) & 1u)) >> 16);   // RNE
}
__device__ __forceinline__ float rdlane(float v, int lane) {
    return __int_as_float(__builtin_amdgcn_readlane(__float_as_int(v), lane));
}

// ---------------- bucket histogram ----------------

__global__ __launch_bounds__(512) void bhist_k(const int* __restrict__ dst,
                                               int* __restrict__ bcnt) {
    __shared__ int hist[NB];
    int t = threadIdx.x;
    long e0 = (long)blockIdx.x * CH;
    int cnt = (int)min((long)CH, (long)EE - e0);
    for (int i = t; i < NB; i += 512) hist[i] = 0;
    __syncthreads();
    for (int i = t; i < cnt; i += 512) atomicAdd(&hist[dst[e0 + i] >> 8], 1);
    __syncthreads();
    for (int i = t; i < NB; i += 512) {
        int v = hist[i];
        if (v > 0) atomicAdd(&bcnt[i], v);
    }
}

__global__ void bucketscan_k(const int* __restrict__ bcnt, int* __restrict__ bucketBase,
                             int* __restrict__ gcursor) {
    __shared__ int s[512];
    int t = threadIdx.x;
    int c = (t < NB) ? bcnt[t] : 0;
    s[t] = c;
    __syncthreads();
    for (int off = 1; off < 512; off <<= 1) {
        int v = (t >= off) ? s[t - off] : 0;
        __syncthreads();
        s[t] += v;
        __syncthreads();
    }
    if (t < NB) {
        int base = s[t] - c;
        bucketBase[t] = base;
        gcursor[t] = base;
    }
    if (t == 0) bucketBase[NB] = EE;
}

// ---------------- partition: edges -> bucket-grouped packed pairs ----------------

__global__ __launch_bounds__(512) void partition_k(const int* __restrict__ src,
                                                   const int* __restrict__ dst,
                                                   int* __restrict__ gcursor,
                                                   u32* __restrict__ pairs) {
    __shared__ int hist[NB];
    __shared__ int lbase[NB];
    __shared__ int gbase[NB];
    __shared__ int scanbuf[512];
    __shared__ u32 stag[CH];
    __shared__ u16 stagb[CH];
    int t = threadIdx.x;
    long e0 = (long)blockIdx.x * CH;
    int cnt = (int)min((long)CH, (long)EE - e0);

    for (int i = t; i < NB; i += 512) hist[i] = 0;
    __syncthreads();

    int myb[16], myloc[16];
    u32 myp[16];
#pragma unroll
    for (int r = 0; r < 16; ++r) {
        int i = t + (r << 9);
        if (i < cnt) {
            int s = src[e0 + i], d = dst[e0 + i];
            int b = d >> 8;
            myb[r] = b;
            myp[r] = ((u32)s << 8) | (u32)(d & 255);
            myloc[r] = atomicAdd(&hist[b], 1);
        } else {
            myb[r] = -1;
            myloc[r] = 0;
            myp[r] = 0;
        }
    }
    __syncthreads();

    scanbuf[t] = (t < NB) ? hist[t] : 0;
    __syncthreads();
    for (int off = 1; off < 512; off <<= 1) {
        int v = (t >= off) ? scanbuf[t - off] : 0;
        __syncthreads();
        scanbuf[t] += v;
        __syncthreads();
    }
    if (t < NB) {
        lbase[t] = scanbuf[t] - hist[t];
        gbase[t] = (hist[t] > 0) ? atomicAdd(&gcursor[t], hist[t]) : 0;
    }
    __syncthreads();

#pragma unroll
    for (int r = 0; r < 16; ++r) {
        if (myb[r] >= 0) {
            int pos = lbase[myb[r]] + myloc[r];
            stag[pos] = myp[r];
            stagb[pos] = (u16)myb[r];
        }
    }
    __syncthreads();

    for (int i = t; i < cnt; i += 512) {
        int b = stagb[i];
        pairs[gbase[b] + (i - lbase[b])] = stag[i];
    }
}

// ---------------- per-bucket CSR fill ----------------

__global__ __launch_bounds__(512) void csrfill_k(const int* __restrict__ bucketBase,
                                                 const u32* __restrict__ pairs,
                                                 int* __restrict__ rowptr,
                                                 float* __restrict__ dinv,
                                                 int* __restrict__ srcS) {
    __shared__ int sb[256];
    __shared__ int sdeg[256];
    __shared__ int lcur[256];
    int b = blockIdx.x, t = threadIdx.x;
    int n0 = b << 8;
    int gb = bucketBase[b];
    int gend = bucketBase[b + 1];

    if (t < 256) sb[t] = 0;
    __syncthreads();

    for (int idx = gb + t; idx < gend; idx += 512) atomicAdd(&sb[pairs[idx] & 255u], 1);
    __syncthreads();

    int d = (t < 256) ? sb[t] : 0;
    if (t < 256) {
        sdeg[t] = d;
        int n = n0 + t;
        if (n < NN) dinv[n] = rsqrtf((float)(d + 1));
    }
    __syncthreads();
    for (int off = 1; off < 256; off <<= 1) {
        int v = 0;
        if (t < 256 && t >= off) v = sb[t - off];
        __syncthreads();
        if (t < 256) sb[t] += v;
        __syncthreads();
    }
    if (t < 256) {
        int excl = sb[t] - sdeg[t];
        int n = n0 + t;
        if (n < NN) rowptr[n] = gb + excl;
        lcur[t] = excl;
    }
    if (b == 0 && t == 0) rowptr[NN] = EE;
    __syncthreads();

    for (int idx = gb + t; idx < gend; idx += 512) {
        u32 p = pairs[idx];
        int dl = (int)(p & 255u);
        int slot = atomicAdd(&lcur[dl], 1);
        srcS[gb + slot] = (int)(p >> 8);
    }
}

// ---------------- layer 1 dense ----------------

__global__ void xw1_k(const float* __restrict__ x, const float* __restrict__ W1,
                      const float* __restrict__ dinv, u16* __restrict__ hs) {
    __shared__ float Ws[IN_DIM * HDIM];
    __shared__ float xs[4 * IN_DIM];
    int t = threadIdx.x;
    for (int i = t; i < IN_DIM * HDIM; i += 256) Ws[i] = W1[i];
    if (t < 4 * IN_DIM) {
        int n = blockIdx.x * 4 + (t >> 4);
        xs[t] = (n < NN) ? x[(size_t)blockIdx.x * 4 * IN_DIM + t] : 0.f;
    }
    __syncthreads();
    int n = blockIdx.x * 4 + (t >> 6);
    int j = t & 63, w = t >> 6;
    if (n >= NN) return;
    float acc = 0.f;
#pragma unroll
    for (int k = 0; k < IN_DIM; k++) acc = fmaf(xs[w * IN_DIM + k], Ws[k * HDIM + j], acc);
    hs[(size_t)n * HDIM + j] = f2bf(acc * dinv[n]);
}

// ---------------- wide gather core: 8 rows per wave instruction ----------------
// lane L: r = L>>3 (edge sub-index), c = L&7 (16B chunk of row)
// acc[0..7] = partial sums of features 8c..8c+7 over edges with sub-index r

#define GATHER_NODE(acc, n, beg, end)                                              \
    {                                                                              \
        if (r == 0) {                                                              \
            uint4 v = *(const uint4*)(hs + ((size_t)(n) << 6) + (c << 3));         \
            ACCUM8(acc, v);                                                        \
        }                                                                          \
        for (int e0 = (beg); e0 < (end); e0 += 32) {                               \
            int eA = e0 + r, eB = eA + 8, eC = eA + 16, eD = eA + 24;              \
            int iA = srcS[eA < (end) ? eA : (beg)];                                \
            int iB = srcS[eB < (end) ? eB : (beg)];                                \
            int iC = srcS[eC < (end) ? eC : (beg)];                                \
            int iD = srcS[eD < (end) ? eD : (beg)];                                \
            uint4 vA = *(const uint4*)(hs + ((size_t)iA << 6) + (c << 3));         \
            uint4 vB = *(const uint4*)(hs + ((size_t)iB << 6) + (c << 3));         \
            uint4 vC = *(const uint4*)(hs + ((size_t)iC << 6) + (c << 3));         \
            uint4 vD = *(const uint4*)(hs + ((size_t)iD << 6) + (c << 3));         \
            if (eA < (end)) ACCUM8(acc, vA);                                       \
            if (eB < (end)) ACCUM8(acc, vB);                                       \
            if (eC < (end)) ACCUM8(acc, vC);                                       \
            if (eD < (end)) ACCUM8(acc, vD);                                       \
        }                                                                          \
        _Pragma("unroll")                                                          \
        for (int j = 0; j < 8; j++) {                                              \
            float a = acc[j];                                                      \
            a += __shfl_xor(a, 8);                                                 \
            a += __shfl_xor(a, 16);                                                \
            a += __shfl_xor(a, 32);                                                \
            acc[j] = a;                                                            \
        }                                                                          \
    }

#define ACCUM8(acc, v)                       \
    {                                        \
        acc[0] += bf_lo(v.x);                \
        acc[1] += bf_hi(v.x);                \
        acc[2] += bf_lo(v.y);                \
        acc[3] += bf_hi(v.y);                \
        acc[4] += bf_lo(v.z);                \
        acc[5] += bf_hi(v.z);                \
        acc[6] += bf_lo(v.w);                \
        acc[7] += bf_hi(v.w);                \
    }

// ---------------- agg layer 1 + @W2 + pre-scale (no LDS; W2 column in VGPRs) ------
// 4 waves/block, 4 nodes/wave -> 16 nodes/block

__global__ __launch_bounds__(256) void agg1w2_k(const u16* __restrict__ hs,
                                                const int* __restrict__ rowptr,
                                                const int* __restrict__ srcS,
                                                const float* __restrict__ dinv,
                                                const float* __restrict__ b1,
                                                const float* __restrict__ W2,
                                                u16* __restrict__ hs2) {
    int t = threadIdx.x;
    int lane = t & 63, w = t >> 6;
    int r = lane >> 3, c = lane & 7;
    int nbase = blockIdx.x * 16 + w * 4;

    float wcol[64];
#pragma unroll
    for (int k = 0; k < 64; k++) wcol[k] = W2[k * HDIM + lane];

    const float4* b14 = (const float4*)b1;
    float4 p0 = b14[c * 2], p1 = b14[c * 2 + 1];
    float b1v[8] = {p0.x, p0.y, p0.z, p0.w, p1.x, p1.y, p1.z, p1.w};

    for (int ni = 0; ni < 4; ++ni) {
        int n = nbase + ni;
        int beg = rowptr[n], end = rowptr[n + 1];
        float dn = dinv[n];
        float acc[8] = {0.f, 0.f, 0.f, 0.f, 0.f, 0.f, 0.f, 0.f};
        GATHER_NODE(acc, n, beg, end);

        float h[8];
#pragma unroll
        for (int j = 0; j < 8; j++) h[j] = fmaxf(fmaf(acc[j], dn, b1v[j]), 0.f);

        float out = 0.f;
#pragma unroll
        for (int f = 0; f < 64; f++) out = fmaf(rdlane(h[f & 7], f >> 3), wcol[f], out);

        hs2[(size_t)n * HDIM + lane] = f2bf(out * dn);
    }
}

// ---------------- agg layer 2 + relu + global_add_pool (1 node/wave) ----------------

__global__ __launch_bounds__(256) void agg_pool_k(const u16* __restrict__ hs,
                                                  const int* __restrict__ rowptr,
                                                  const int* __restrict__ srcS,
                                                  const float* __restrict__ dinv,
                                                  const float* __restrict__ b2,
                                                  const int* __restrict__ batch,
                                                  float* __restrict__ g) {
    int t = threadIdx.x;
    int lane = t & 63;
    int n = blockIdx.x * 4 + (t >> 6);
    int r = lane >> 3, c = lane & 7;
    int f = (c << 3) + r;
    float b2f = b2[f];

    int beg = rowptr[n], end = rowptr[n + 1];
    float acc[8] = {0.f, 0.f, 0.f, 0.f, 0.f, 0.f, 0.f, 0.f};
    GATHER_NODE(acc, n, beg, end);

    float mine = 0.f;
#pragma unroll
    for (int j = 0; j < 8; j++) mine = (j == r) ? acc[j] : mine;

    float v = fmaf(mine, dinv[n], b2f);
    v = fmaxf(v, 0.f);
    unsafeAtomicAdd(&g[(size_t)batch[n] * HDIM + f], v);
}

__global__ void final_k(const float* __restrict__ g, const float* __restrict__ Wl,
                        const float* __restrict__ bl, float* __restrict__ out) {
    int t = threadIdx.x;
    int gi = t >> 2, cc = t & 3;
    float acc = bl[cc];
#pragma unroll
    for (int k = 0; k < HDIM; k++) acc = fmaf(g[gi * HDIM + k], Wl[k * CDIM + cc], acc);
    out[gi * CDIM + cc] = acc;
}

// ---------------- launch ----------------

extern "C" void kernel_launch(void* const* d_in, const int* in_sizes, int n_in,
                              void* d_out, int out_size, void* d_ws, size_t ws_size,
                              hipStream_t stream) {
    const float* x   = (const float*)d_in[0];
    const int*   ei  = (const int*)d_in[1];
    const int*   src = ei;
    const int*   dst = ei + EE;
    const int*   batch = (const int*)d_in[2];
    const float* W1 = (const float*)d_in[3];
    const float* b1 = (const float*)d_in[4];
    const float* W2 = (const float*)d_in[5];
    const float* b2 = (const float*)d_in[6];
    const float* Wl = (const float*)d_in[7];
    const float* bl = (const float*)d_in[8];
    float* out = (float*)d_out;

    char* w = (char*)d_ws;
    auto alloc = [&](size_t bytes) -> char* {
        char* p = w;
        w += (bytes + 255) & ~(size_t)255;
        return p;
    };
    int*   bcnt       = (int*)alloc((size_t)NB * 4);
    int*   bucketBase = (int*)alloc((size_t)(NB + 1) * 4);
    int*   gcursor    = (int*)alloc((size_t)NB * 4);
    u32*   pairs      = (u32*)alloc((size_t)EE * 4);
    int*   srcS       = (int*)alloc((size_t)EE * 4);
    int*   rowptr     = (int*)alloc((size_t)(NN + 1) * 4);
    float* dinv       = (float*)alloc((size_t)NN * 4);
    u16*   hsA        = (u16*)alloc((size_t)NN * HDIM * 2);
    u16*   hsB        = (u16*)alloc((size_t)NN * HDIM * 2);
    float* g          = (float*)alloc((size_t)GG * HDIM * 4);

    hipMemsetAsync(bcnt, 0, (size_t)NB * 4, stream);
    hipMemsetAsync(g, 0, (size_t)GG * HDIM * 4, stream);

    const int NCHUNK = (EE + CH - 1) / CH;
    bhist_k<<<NCHUNK, 512, 0, stream>>>(dst, bcnt);
    bucketscan_k<<<1, 512, 0, stream>>>(bcnt, bucketBase, gcursor);
    partition_k<<<NCHUNK, 512, 0, stream>>>(src, dst, gcursor, pairs);
    csrfill_k<<<NB, 512, 0, stream>>>(bucketBase, pairs, rowptr, dinv, srcS);

    xw1_k<<<(NN + 3) / 4, 256, 0, stream>>>(x, W1, dinv, hsA);
    agg1w2_k<<<NN / 16, 256, 0, stream>>>(hsA, rowptr, srcS, dinv, b1, W2, hsB);
    agg_pool_k<<<NN / 4, 256, 0, stream>>>(hsB, rowptr, srcS, dinv, b2, batch, g);
    final_k<<<1, 512, 0, stream>>>(g, Wl, bl, out);
}

// Round 5
// 285.282 us; speedup vs baseline: 2.8410x; 1.1516x over previous
//
#include <hip/hip_runtime.h>
#include <hip/hip_bf16.h>

#define NN 100000
#define EE 3200000
#define GG 128
#define IN_DIM 16
#define HDIM 64
#define CDIM 4

#define RN 256                    // nodes per bucket
#define NB ((NN + RN - 1) / RN)   // 391 buckets
#define CH 8192                   // edges per partition block

typedef unsigned short u16;
typedef unsigned int u32;

__device__ __forceinline__ float bf_lo(u32 w) { return __uint_as_float(w << 16); }
__device__ __forceinline__ float bf_hi(u32 w) { return __uint_as_float(w & 0xFFFF0000u); }
__device__ __forceinline__ u16 f2bf(float f) {
    u32 x = __float_as_uint(f);
    return (u16)((x + 0x7FFFu + ((x >> 16) & 1u)) >> 16);   // RNE
}
__device__ __forceinline__ float rdlane(float v, int lane) {
    return __int_as_float(__builtin_amdgcn_readlane(__float_as_int(v), lane));
}

// ---------------- bucket histogram ----------------

__global__ __launch_bounds__(512) void bhist_k(const int* __restrict__ dst,
                                               int* __restrict__ bcnt) {
    __shared__ int hist[NB];
    int t = threadIdx.x;
    long e0 = (long)blockIdx.x * CH;
    int cnt = (int)min((long)CH, (long)EE - e0);
    for (int i = t; i < NB; i += 512) hist[i] = 0;
    __syncthreads();
    for (int i = t; i < cnt; i += 512) atomicAdd(&hist[dst[e0 + i] >> 8], 1);
    __syncthreads();
    for (int i = t; i < NB; i += 512) {
        int v = hist[i];
        if (v > 0) atomicAdd(&bcnt[i], v);
    }
}

__global__ void bucketscan_k(const int* __restrict__ bcnt, int* __restrict__ bucketBase,
                             int* __restrict__ gcursor) {
    __shared__ int s[512];
    int t = threadIdx.x;
    int c = (t < NB) ? bcnt[t] : 0;
    s[t] = c;
    __syncthreads();
    for (int off = 1; off < 512; off <<= 1) {
        int v = (t >= off) ? s[t - off] : 0;
        __syncthreads();
        s[t] += v;
        __syncthreads();
    }
    if (t < NB) {
        int base = s[t] - c;
        bucketBase[t] = base;
        gcursor[t] = base;
    }
    if (t == 0) bucketBase[NB] = EE;
}

// ---------------- partition: edges -> bucket-grouped packed pairs ----------------

__global__ __launch_bounds__(512) void partition_k(const int* __restrict__ src,
                                                   const int* __restrict__ dst,
                                                   int* __restrict__ gcursor,
                                                   u32* __restrict__ pairs) {
    __shared__ int hist[NB];
    __shared__ int lbase[NB];
    __shared__ int gbase[NB];
    __shared__ int scanbuf[512];
    __shared__ u32 stag[CH];
    __shared__ u16 stagb[CH];
    int t = threadIdx.x;
    long e0 = (long)blockIdx.x * CH;
    int cnt = (int)min((long)CH, (long)EE - e0);

    for (int i = t; i < NB; i += 512) hist[i] = 0;
    __syncthreads();

    int myb[16], myloc[16];
    u32 myp[16];
#pragma unroll
    for (int r = 0; r < 16; ++r) {
        int i = t + (r << 9);
        if (i < cnt) {
            int s = src[e0 + i], d = dst[e0 + i];
            int b = d >> 8;
            myb[r] = b;
            myp[r] = ((u32)s << 8) | (u32)(d & 255);
            myloc[r] = atomicAdd(&hist[b], 1);
        } else {
            myb[r] = -1;
            myloc[r] = 0;
            myp[r] = 0;
        }
    }
    __syncthreads();

    scanbuf[t] = (t < NB) ? hist[t] : 0;
    __syncthreads();
    for (int off = 1; off < 512; off <<= 1) {
        int v = (t >= off) ? scanbuf[t - off] : 0;
        __syncthreads();
        scanbuf[t] += v;
        __syncthreads();
    }
    if (t < NB) {
        lbase[t] = scanbuf[t] - hist[t];
        gbase[t] = (hist[t] > 0) ? atomicAdd(&gcursor[t], hist[t]) : 0;
    }
    __syncthreads();

#pragma unroll
    for (int r = 0; r < 16; ++r) {
        if (myb[r] >= 0) {
            int pos = lbase[myb[r]] + myloc[r];
            stag[pos] = myp[r];
            stagb[pos] = (u16)myb[r];
        }
    }
    __syncthreads();

    for (int i = t; i < cnt; i += 512) {
        int b = stagb[i];
        pairs[gbase[b] + (i - lbase[b])] = stag[i];
    }
}

// ---------------- per-bucket CSR fill ----------------

__global__ __launch_bounds__(512) void csrfill_k(const int* __restrict__ bucketBase,
                                                 const u32* __restrict__ pairs,
                                                 int* __restrict__ rowptr,
                                                 float* __restrict__ dinv,
                                                 int* __restrict__ srcS) {
    __shared__ int sb[256];
    __shared__ int sdeg[256];
    __shared__ int lcur[256];
    int b = blockIdx.x, t = threadIdx.x;
    int n0 = b << 8;
    int gb = bucketBase[b];
    int gend = bucketBase[b + 1];

    if (t < 256) sb[t] = 0;
    __syncthreads();

    for (int idx = gb + t; idx < gend; idx += 512) atomicAdd(&sb[pairs[idx] & 255u], 1);
    __syncthreads();

    int d = (t < 256) ? sb[t] : 0;
    if (t < 256) {
        sdeg[t] = d;
        int n = n0 + t;
        if (n < NN) dinv[n] = rsqrtf((float)(d + 1));
    }
    __syncthreads();
    for (int off = 1; off < 256; off <<= 1) {
        int v = 0;
        if (t < 256 && t >= off) v = sb[t - off];
        __syncthreads();
        if (t < 256) sb[t] += v;
        __syncthreads();
    }
    if (t < 256) {
        int excl = sb[t] - sdeg[t];
        int n = n0 + t;
        if (n < NN) rowptr[n] = gb + excl;
        lcur[t] = excl;
    }
    if (b == 0 && t == 0) rowptr[NN] = EE;
    __syncthreads();

    for (int idx = gb + t; idx < gend; idx += 512) {
        u32 p = pairs[idx];
        int dl = (int)(p & 255u);
        int slot = atomicAdd(&lcur[dl], 1);
        srcS[gb + slot] = (int)(p >> 8);
    }
}

// ---------------- xs = x * dinv, bf16 (3.2 MB table, L2-resident) ----------------
// thread i handles 4 feats of node i>>2: read float4, write 8B

__global__ void xs_k(const float* __restrict__ x, const float* __restrict__ dinv,
                     u16* __restrict__ xs) {
    int i = blockIdx.x * 256 + threadIdx.x;
    if (i >= NN * 4) return;
    int n = i >> 2;
    float dn = dinv[n];
    float4 v = ((const float4*)x)[i];
    u32 p0 = (u32)f2bf(v.x * dn) | ((u32)f2bf(v.y * dn) << 16);
    u32 p1 = (u32)f2bf(v.z * dn) | ((u32)f2bf(v.w * dn) << 16);
    uint2 pk; pk.x = p0; pk.y = p1;
    ((uint2*)xs)[i] = pk;
}

#define ACCUM8(acc, v)                       \
    {                                        \
        acc[0] += bf_lo(v.x);                \
        acc[1] += bf_hi(v.x);                \
        acc[2] += bf_lo(v.y);                \
        acc[3] += bf_hi(v.y);                \
        acc[4] += bf_lo(v.z);                \
        acc[5] += bf_hi(v.z);                \
        acc[6] += bf_lo(v.w);                \
        acc[7] += bf_hi(v.w);                \
    }

// ---------------- pass 1: aggregate 16-dim xs, then @W1 +b1, relu, @W2, *dinv ----------
// lane: c = lane&1 (16B chunk of 32B row), r = lane>>1 (32 edge slots/instr)
// 4 waves/block * 4 nodes/wave = 16 nodes/block

__global__ __launch_bounds__(256) void aggx_k(const u16* __restrict__ xs,
                                              const int* __restrict__ rowptr,
                                              const int* __restrict__ srcS,
                                              const float* __restrict__ dinv,
                                              const float* __restrict__ b1,
                                              const float* __restrict__ W1,
                                              const float* __restrict__ W2,
                                              u16* __restrict__ hs2) {
    int t = threadIdx.x;
    int lane = t & 63, w = t >> 6;
    int c = lane & 1, r = lane >> 1;
    int nbase = blockIdx.x * 16 + w * 4;

    float w1c[16];
#pragma unroll
    for (int k = 0; k < 16; k++) w1c[k] = W1[k * HDIM + lane];
    float wcol[64];
#pragma unroll
    for (int k = 0; k < 64; k++) wcol[k] = W2[k * HDIM + lane];
    float b1l = b1[lane];

    for (int ni = 0; ni < 4; ++ni) {
        int n = nbase + ni;
        int beg = rowptr[n], end = rowptr[n + 1];
        float dn = dinv[n];
        float acc[8] = {0.f, 0.f, 0.f, 0.f, 0.f, 0.f, 0.f, 0.f};
        if (r == 0) {   // self-loop
            uint4 v = *(const uint4*)(xs + ((size_t)n << 4) + (c << 3));
            ACCUM8(acc, v);
        }
        for (int e0 = beg; e0 < end; e0 += 32) {
            int e = e0 + r;
            int idx = srcS[e < end ? e : beg];
            uint4 v = *(const uint4*)(xs + ((size_t)idx << 4) + (c << 3));
            if (e < end) ACCUM8(acc, v);
        }
        // reduce over the 32 edge slots (keep chunk parity)
#pragma unroll
        for (int j = 0; j < 8; j++) {
            float a = acc[j];
            a += __shfl_xor(a, 2);
            a += __shfl_xor(a, 4);
            a += __shfl_xor(a, 8);
            a += __shfl_xor(a, 16);
            a += __shfl_xor(a, 32);
            acc[j] = a;
        }
        float oth[8];
#pragma unroll
        for (int j = 0; j < 8; j++) oth[j] = __shfl_xor(acc[j], 1);

        // agg16 @ W1 column(lane): feats 0-7 = (c?oth:acc), feats 8-15 = (c?acc:oth)
        float dot = 0.f;
#pragma unroll
        for (int j = 0; j < 8; j++) {
            float lo = c ? oth[j] : acc[j];
            float hi = c ? acc[j] : oth[j];
            dot = fmaf(lo, w1c[j], dot);
            dot = fmaf(hi, w1c[j + 8], dot);
        }
        float h = fmaxf(fmaf(dot, dn, b1l), 0.f);   // h1[lane] for node n

        float out = 0.f;
#pragma unroll
        for (int f = 0; f < 64; f++) out = fmaf(rdlane(h, f), wcol[f], out);
        hs2[(size_t)n * HDIM + lane] = f2bf(out * dn);
    }
}

// ---------------- pass 2: 64-dim gather + relu + global_add_pool ----------------
// lane: r = lane>>3 (8 edge slots), c = lane&7 (16B chunk of 128B row)

#define GATHER_NODE(acc, n, beg, end)                                              \
    {                                                                              \
        if (r == 0) {                                                              \
            uint4 v = *(const uint4*)(hs + ((size_t)(n) << 6) + (c << 3));         \
            ACCUM8(acc, v);                                                        \
        }                                                                          \
        for (int e0 = (beg); e0 < (end); e0 += 32) {                               \
            int eA = e0 + r, eB = eA + 8, eC = eA + 16, eD = eA + 24;              \
            int iA = srcS[eA < (end) ? eA : (beg)];                                \
            int iB = srcS[eB < (end) ? eB : (beg)];                                \
            int iC = srcS[eC < (end) ? eC : (beg)];                                \
            int iD = srcS[eD < (end) ? eD : (beg)];                                \
            uint4 vA = *(const uint4*)(hs + ((size_t)iA << 6) + (c << 3));         \
            uint4 vB = *(const uint4*)(hs + ((size_t)iB << 6) + (c << 3));         \
            uint4 vC = *(const uint4*)(hs + ((size_t)iC << 6) + (c << 3));         \
            uint4 vD = *(const uint4*)(hs + ((size_t)iD << 6) + (c << 3));         \
            if (eA < (end)) ACCUM8(acc, vA);                                       \
            if (eB < (end)) ACCUM8(acc, vB);                                       \
            if (eC < (end)) ACCUM8(acc, vC);                                       \
            if (eD < (end)) ACCUM8(acc, vD);                                       \
        }                                                                          \
        _Pragma("unroll")                                                          \
        for (int j = 0; j < 8; j++) {                                              \
            float a = acc[j];                                                      \
            a += __shfl_xor(a, 8);                                                 \
            a += __shfl_xor(a, 16);                                                \
            a += __shfl_xor(a, 32);                                                \
            acc[j] = a;                                                            \
        }                                                                          \
    }

__global__ __launch_bounds__(256) void agg_pool_k(const u16* __restrict__ hs,
                                                  const int* __restrict__ rowptr,
                                                  const int* __restrict__ srcS,
                                                  const float* __restrict__ dinv,
                                                  const float* __restrict__ b2,
                                                  const int* __restrict__ batch,
                                                  float* __restrict__ g) {
    int t = threadIdx.x;
    int lane = t & 63;
    int n = blockIdx.x * 4 + (t >> 6);
    int r = lane >> 3, c = lane & 7;
    int f = (c << 3) + r;
    float b2f = b2[f];

    int beg = rowptr[n], end = rowptr[n + 1];
    float acc[8] = {0.f, 0.f, 0.f, 0.f, 0.f, 0.f, 0.f, 0.f};
    GATHER_NODE(acc, n, beg, end);

    float mine = 0.f;
#pragma unroll
    for (int j = 0; j < 8; j++) mine = (j == r) ? acc[j] : mine;

    float v = fmaf(mine, dinv[n], b2f);
    v = fmaxf(v, 0.f);
    unsafeAtomicAdd(&g[(size_t)batch[n] * HDIM + f], v);
}

__global__ void final_k(const float* __restrict__ g, const float* __restrict__ Wl,
                        const float* __restrict__ bl, float* __restrict__ out) {
    int t = threadIdx.x;
    int gi = t >> 2, cc = t & 3;
    float acc = bl[cc];
#pragma unroll
    for (int k = 0; k < HDIM; k++) acc = fmaf(g[gi * HDIM + k], Wl[k * CDIM + cc], acc);
    out[gi * CDIM + cc] = acc;
}

// ---------------- launch ----------------

extern "C" void kernel_launch(void* const* d_in, const int* in_sizes, int n_in,
                              void* d_out, int out_size, void* d_ws, size_t ws_size,
                              hipStream_t stream) {
    const float* x   = (const float*)d_in[0];
    const int*   ei  = (const int*)d_in[1];
    const int*   src = ei;
    const int*   dst = ei + EE;
    const int*   batch = (const int*)d_in[2];
    const float* W1 = (const float*)d_in[3];
    const float* b1 = (const float*)d_in[4];
    const float* W2 = (const float*)d_in[5];
    const float* b2 = (const float*)d_in[6];
    const float* Wl = (const float*)d_in[7];
    const float* bl = (const float*)d_in[8];
    float* out = (float*)d_out;

    char* w = (char*)d_ws;
    auto alloc = [&](size_t bytes) -> char* {
        char* p = w;
        w += (bytes + 255) & ~(size_t)255;
        return p;
    };
    int*   bcnt       = (int*)alloc((size_t)NB * 4);
    int*   bucketBase = (int*)alloc((size_t)(NB + 1) * 4);
    int*   gcursor    = (int*)alloc((size_t)NB * 4);
    u32*   pairs      = (u32*)alloc((size_t)EE * 4);
    int*   srcS       = (int*)alloc((size_t)EE * 4);
    int*   rowptr     = (int*)alloc((size_t)(NN + 1) * 4);
    float* dinv       = (float*)alloc((size_t)NN * 4);
    u16*   xs         = (u16*)alloc((size_t)NN * IN_DIM * 2);
    u16*   hsB        = (u16*)alloc((size_t)NN * HDIM * 2);
    float* g          = (float*)alloc((size_t)GG * HDIM * 4);

    hipMemsetAsync(bcnt, 0, (size_t)NB * 4, stream);
    hipMemsetAsync(g, 0, (size_t)GG * HDIM * 4, stream);

    const int NCHUNK = (EE + CH - 1) / CH;
    bhist_k<<<NCHUNK, 512, 0, stream>>>(dst, bcnt);
    bucketscan_k<<<1, 512, 0, stream>>>(bcnt, bucketBase, gcursor);
    partition_k<<<NCHUNK, 512, 0, stream>>>(src, dst, gcursor, pairs);
    csrfill_k<<<NB, 512, 0, stream>>>(bucketBase, pairs, rowptr, dinv, srcS);

    xs_k<<<(NN * 4 + 255) / 256, 256, 0, stream>>>(x, dinv, xs);
    aggx_k<<<NN / 16, 256, 0, stream>>>(xs, rowptr, srcS, dinv, b1, W1, W2, hsB);
    agg_pool_k<<<NN / 4, 256, 0, stream>>>(hsB, rowptr, srcS, dinv, b2, batch, g);
    final_k<<<1, 512, 0, stream>>>(g, Wl, bl, out);
}